// Round 10
// baseline (3461.720 us; speedup 1.0000x reference)
//
#include <hip/hip_runtime.h>
#include <math.h>

typedef __bf16 bf16_t;
typedef __bf16 bf16x8 __attribute__((ext_vector_type(8)));
typedef __bf16 bf16x4 __attribute__((ext_vector_type(4)));
typedef float f32x4 __attribute__((ext_vector_type(4)));
typedef float f32x16 __attribute__((ext_vector_type(16)));
typedef unsigned int u32;

static constexpr int kBd = 8, kS = 2048, kH = 1024, kDH = 4096, kE = 8;
static constexpr int kM = kBd * kS;        // 16384 rows
static constexpr float kScale = 0.03125f;  // 1/sqrt(1024)

__device__ __forceinline__ void gload_lds16(const void* g, void* l) {
  __builtin_amdgcn_global_load_lds(
      (const __attribute__((address_space(1))) u32*)g,
      (__attribute__((address_space(3))) u32*)l, 16, 0, 0);
}

// ---------------- conversion kernels ----------------
__global__ __launch_bounds__(256) void cvt_flat_kernel(const float* __restrict__ in,
                                                       bf16_t* __restrict__ out, int n4) {
  int i = blockIdx.x * 256 + threadIdx.x;
  if (i >= n4) return;
  f32x4 v = *(const f32x4*)(in + (size_t)i * 4);
  bf16x4 o;
#pragma unroll
  for (int j = 0; j < 4; ++j) o[j] = (bf16_t)v[j];
  *(bf16x4*)(out + (size_t)i * 4) = o;
}

// out[c][r] = bf16(in[r][c]); grid (C/32, R/32)
__global__ __launch_bounds__(256) void transpose_cvt_kernel(
    const float* __restrict__ in, bf16_t* __restrict__ out, int R, int C) {
  __shared__ float tile[32][33];
  int tx = threadIdx.x & 31, ty = threadIdx.x >> 5;  // 32 x 8
  int c0 = blockIdx.x * 32, r0 = blockIdx.y * 32;
#pragma unroll
  for (int yy = 0; yy < 4; ++yy)
    tile[ty + yy * 8][tx] = in[(size_t)(r0 + ty + yy * 8) * C + c0 + tx];
  __syncthreads();
#pragma unroll
  for (int yy = 0; yy < 4; ++yy)
    out[(size_t)(c0 + ty + yy * 8) * R + r0 + tx] = (bf16_t)tile[tx][ty + yy * 8];
}

// ---- 256x256x64 GEMM, 32x32x16 MFMA, round-9 overlap schedule ----
// C = A[M,K]*B[K,N], Bt = B^T [N,K] bf16.
// LDS 160KB: A triple-buf (3x32KB, buf=t%3) + B dbuf (2x32KB, buf=t&1).
// Logical tile [256 rows][64 K] row-major (128B/row), swizzle byte^=((row&7)<<4).
// Per wave (2Mx4N grid): out 128x64 = 4x2 blocks of 32x32; 24 ds_read_b128 +
// 32 v_mfma_f32_32x32x16_bf16 per K-tile. Reads issue-early, compiler counted
// waits; 1 barrier + counted vmcnt(8) gate per tile (vmcnt(0) tail).
// MODE 0: outb = bf16(relu(acc+bias))
// MODE 1: eo = acc+bias; nb = bin_f + 0.5*eo; bout_f = nb; bout_b = bf16(nb); stacked = bf16(eo)
// MODE 2: outb = bf16(acc+bias)
// MODE 3: yout = acc + bias + xres   (f32)
// MODE 4: eo = acc+bias; nb = (float)bin_b + 0.5*eo; bout_b = bf16(nb); stacked = bf16(eo)
template <int MODE>
__global__ __launch_bounds__(512, 2) void gemm256_kernel(
    const bf16_t* __restrict__ A, const bf16_t* __restrict__ Bt,
    int M, int N, int K, int nwg,
    const float* __restrict__ bias,
    bf16_t* __restrict__ outb,
    const float* __restrict__ bin_f, float* __restrict__ bout_f,
    const bf16_t* __restrict__ bin_b, bf16_t* __restrict__ bout_b,
    bf16_t* __restrict__ stacked,
    const float* __restrict__ xres, float* __restrict__ yout,
    const int* __restrict__ curp, int expert_i) {
  if ((MODE == 0 || MODE == 1 || MODE == 4) && expert_i > *curp) return;
  extern __shared__ char lds_buf[];           // 163840 bytes
  char* Abase = lds_buf;                      // 3 x 32KB
  char* Bbase = lds_buf + 98304;              // 2 x 32KB
  const int tid = threadIdx.x;
  const int lane = tid & 63, wid = tid >> 6;
  const int wr = wid >> 2, wc = wid & 3;      // 2(M) x 4(N) waves; 128x64 per wave
  const int l5 = lane & 31;
  // per-lane swizzled k-offsets: kx[ks] = ((ks*32 + (l>>5)*16) ^ ((l&7)<<4))
  const int kxb = (lane >> 5) << 4;
  const int sw = (lane & 7) << 4;
  int kx[4];
#pragma unroll
  for (int ks = 0; ks < 4; ++ks) kx[ks] = ((ks << 5) + kxb) ^ sw;
  // bijective XCD swizzle (all grids here are %8==0)
  const int bid = blockIdx.x;
  const int wg = (bid & 7) * (nwg >> 3) + (bid >> 3);
  const int nMb = M >> 8;
  const int m0 = (wg % nMb) << 8, n0 = (wg / nMb) << 8;
  // staging map: thread q=tid (+512) covers phys 16B chunk q of each 16KB half;
  // phys(row, c) = row*128 + (c ^ ((row&7)<<4))  =>  source col for chunk q:
  const int grow_ = tid >> 3;                                   // 0..63 (+64 for j=1)
  const int gcol_ = (((tid & 7) ^ ((tid >> 3) & 7)) << 3);      // bf16 elems
  const bf16_t* sA[2] = {A + (size_t)(m0 + grow_) * K + gcol_,
                         A + (size_t)(m0 + grow_ + 64) * K + gcol_};
  const bf16_t* sB[2] = {Bt + (size_t)(n0 + grow_) * K + gcol_,
                         Bt + (size_t)(n0 + grow_ + 64) * K + gcol_};
  const size_t rstep = (size_t)128 * K;

#define STAGE(SP, BASE, tau, h)                                               \
  {                                                                           \
    char* d_ = (BASE) + ((h) << 14) + (wid << 10);                            \
    gload_lds16(SP[0] + (size_t)(h)*rstep + (size_t)(tau)*64, d_);            \
    gload_lds16(SP[1] + (size_t)(h)*rstep + (size_t)(tau)*64, d_ + 8192);     \
  }
#define STAGE_A(buf, t, h) STAGE(sA, Abase + (buf)*32768, (t), (h))
#define STAGE_B(t, h) STAGE(sB, Bbase + (((t)&1) << 15), (t), (h))
#define SB0() __builtin_amdgcn_sched_barrier(0)

  f32x16 acc[4][2] = {};
  const int NT = K >> 6;  // K/64, >= 16 here

// GROUP(g, AF, mi): 8 MFMAs for m-blocks at acc[2g.. ] using AF[mi][ks]
#define GROUP(g, AF, mi)                                                       \
  __builtin_amdgcn_s_setprio(1);                                               \
  _Pragma("unroll") for (int ks = 0; ks < 4; ++ks) {                           \
    acc[g][0] = __builtin_amdgcn_mfma_f32_32x32x16_bf16(                       \
        AF[mi][ks], b[0][ks], acc[g][0], 0, 0, 0);                             \
    acc[g][1] = __builtin_amdgcn_mfma_f32_32x32x16_bf16(                       \
        AF[mi][ks], b[1][ks], acc[g][1], 0, 0, 0);                             \
  }                                                                            \
  __builtin_amdgcn_s_setprio(0);

  // prologue: A(0),B(0),A(1),B(1); leave A(1),B(1) (8 loads) in flight
  STAGE_A(0, 0, 0); STAGE_A(0, 0, 1);
  STAGE_B(0, 0); STAGE_B(0, 1);
  STAGE_A(1, 1, 0); STAGE_A(1, 1, 1);
  STAGE_B(1, 0); STAGE_B(1, 1);
  asm volatile("s_waitcnt vmcnt(8)" ::: "memory");
  __builtin_amdgcn_s_barrier();

  int am0 = 0;
  for (int t = 0; t < NT; ++t) {
    int am2 = am0 + 2; if (am2 >= 3) am2 -= 3;
    const char* ArL = Abase + am0 * 32768 + (wr << 14) + l5 * 128;
    const char* BrL = Bbase + ((t & 1) << 15) + (wc << 13) + l5 * 128;
    bf16x8 b[2][4], a01[2][4], a23[2][4];
    const bool st = (t + 2 < NT);
    // --- B reads (FIFO-first, needed for the in-place B restage) ---
#pragma unroll
    for (int nb = 0; nb < 2; ++nb)
#pragma unroll
      for (int ks = 0; ks < 4; ++ks)
        b[nb][ks] = *(const bf16x8*)(BrL + nb * 4096 + kx[ks]);
    SB0();
    // --- A m-blocks 0-1 ---
#pragma unroll
    for (int mb = 0; mb < 2; ++mb)
#pragma unroll
      for (int ks = 0; ks < 4; ++ks)
        a01[mb][ks] = *(const bf16x8*)(ArL + mb * 4096 + kx[ks]);
    SB0();
    // --- stage A(t+2) into disjoint buffer am2 ---
    if (st) { STAGE_A(am2, t + 2, 0); STAGE_A(am2, t + 2, 1); }
    SB0();
    // --- group0; A m-blocks 2-3 reads float under it ---
    GROUP(0, a01, 0);
#pragma unroll
    for (int mb = 0; mb < 2; ++mb)
#pragma unroll
      for (int ks = 0; ks < 4; ++ks)
        a23[mb][ks] = *(const bf16x8*)(ArL + (2 + mb) * 4096 + kx[ks]);
    SB0();
    GROUP(1, a01, 1);
    // --- formal fence: B reads (first 16 with a01) drained; restage B in place ---
    asm volatile("s_waitcnt lgkmcnt(8)" ::: "memory");
    SB0();
    if (st) { STAGE_B(t + 2, 0); STAGE_B(t + 2, 1); }
    SB0();
    GROUP(2, a23, 0);
    GROUP(3, a23, 1);
    // --- counted gate: drains stages of tile t-1 (what tile t+1 reads) ---
    if (t < NT - 2) {
      asm volatile("s_waitcnt vmcnt(8)" ::: "memory");
    } else {
      asm volatile("s_waitcnt vmcnt(0)" ::: "memory");
    }
    __builtin_amdgcn_s_barrier();
    am0 = am0 + 1; if (am0 >= 3) am0 -= 3;
  }
#undef GROUP
#undef STAGE
#undef STAGE_A
#undef STAGE_B
#undef SB0

  // ---- epilogue (32x32 C layout: col=lane&31, row=(reg&3)+8*(reg>>2)+4*(lane>>5)) ----
  const int rbase = (lane >> 5) << 2;
#pragma unroll
  for (int nb = 0; nb < 2; ++nb) {
    const int col = n0 + wc * 64 + nb * 32 + l5;
    const float bv = bias ? bias[col] : 0.0f;
#pragma unroll
    for (int mb = 0; mb < 4; ++mb) {
#pragma unroll
      for (int reg = 0; reg < 16; ++reg) {
        const int row = m0 + wr * 128 + mb * 32 + (reg & 3) + 8 * (reg >> 2) + rbase;
        const size_t idx = (size_t)row * N + col;
        float v = acc[mb][nb][reg] + bv;
        if (MODE == 0) {
          outb[idx] = (bf16_t)(v > 0.0f ? v : 0.0f);
        } else if (MODE == 2) {
          outb[idx] = (bf16_t)v;
        } else if (MODE == 1) {
          float nb2 = bin_f[idx] + 0.5f * v;
          bout_f[idx] = nb2;
          bout_b[idx] = (bf16_t)nb2;
          stacked[idx] = (bf16_t)v;
        } else if (MODE == 4) {
          float nb2 = (float)bin_b[idx] + 0.5f * v;
          bout_b[idx] = (bf16_t)nb2;
          stacked[idx] = (bf16_t)v;
        } else {
          yout[idx] = v + xres[idx];
        }
      }
    }
  }
}

// ---------------- scores + softmax + mix ----------------
__global__ __launch_bounds__(256) void scores_mix_kernel(
    const bf16_t* __restrict__ qk, const bf16_t* __restrict__ q,
    const float* __restrict__ bk, const bf16_t* __restrict__ stacked,
    bf16_t* __restrict__ mix, const int* __restrict__ curp) {
  const int n = *curp + 1;
  int lane = threadIdx.x & 63, wave = threadIdx.x >> 6;
  int m = blockIdx.x * 4 + wave;
  size_t base = (size_t)m * kH + lane * 16;
  int c0 = lane * 16;
  bf16x8 qk0 = *(const bf16x8*)(qk + base);
  bf16x8 qk1 = *(const bf16x8*)(qk + base + 8);
  bf16x8 q0 = *(const bf16x8*)(q + base);
  bf16x8 q1 = *(const bf16x8*)(q + base + 8);
  float sc[kE + 1];
  bf16x8 eo0[kE], eo1[kE];
#pragma unroll
  for (int e = 0; e < kE; ++e) {
    sc[e] = 0.0f;
    if (e < n) {
      size_t sb = (size_t)e * kM * kH + base;
      eo0[e] = *(const bf16x8*)(stacked + sb);
      eo1[e] = *(const bf16x8*)(stacked + sb + 8);
      float d = 0.0f;
#pragma unroll
      for (int j = 0; j < 8; ++j)
        d += (float)eo0[e][j] * (float)qk0[j] + (float)eo1[e][j] * (float)qk1[j];
      sc[e] = d;
    }
  }
  {
    float qb = 0.0f;
#pragma unroll
    for (int j = 0; j < 8; ++j)
      qb += (float)q0[j] * bk[c0 + j] + (float)q1[j] * bk[c0 + 8 + j];
    sc[kE] = qb;
  }
#pragma unroll
  for (int off = 32; off >= 1; off >>= 1)
#pragma unroll
    for (int e = 0; e <= kE; ++e) sc[e] += __shfl_xor(sc[e], off, 64);
  float s[kE];
  float mx = -1e30f;
#pragma unroll
  for (int e = 0; e < kE; ++e)
    if (e < n) {
      s[e] = (sc[e] + sc[kE]) * kScale;
      mx = fmaxf(mx, s[e]);
    }
  float Z = 0.0f;
#pragma unroll
  for (int e = 0; e < kE; ++e)
    if (e < n) {
      s[e] = expf(s[e] - mx);
      Z += s[e];
    }
  float inv = 1.0f / Z;
  float mv[16];
#pragma unroll
  for (int j = 0; j < 16; ++j) mv[j] = 0.0f;
#pragma unroll
  for (int e = 0; e < kE; ++e)
    if (e < n) {
      float w = s[e] * inv;
#pragma unroll
      for (int j = 0; j < 8; ++j) {
        mv[j] += w * (float)eo0[e][j];
        mv[8 + j] += w * (float)eo1[e][j];
      }
    }
  bf16x8 o0, o1;
#pragma unroll
  for (int j = 0; j < 8; ++j) {
    o0[j] = (bf16_t)mv[j];
    o1[j] = (bf16_t)mv[8 + j];
  }
  *(bf16x8*)(mix + base) = o0;
  *(bf16x8*)(mix + base + 8) = o1;
}

// ---------------- LayerNorm ----------------
__global__ __launch_bounds__(256) void layernorm_kernel(
    const float* __restrict__ y, const float* __restrict__ g,
    const float* __restrict__ b, float* __restrict__ out) {
  int lane = threadIdx.x & 63, wave = threadIdx.x >> 6;
  int m = blockIdx.x * 4 + wave;
  size_t base = (size_t)m * kH + lane * 16;
  f32x4 v[4];
#pragma unroll
  for (int j = 0; j < 4; ++j) v[j] = *(const f32x4*)(y + base + j * 4);
  float s = 0.0f, s2 = 0.0f;
#pragma unroll
  for (int j = 0; j < 4; ++j)
#pragma unroll
    for (int t = 0; t < 4; ++t) {
      float u = v[j][t];
      s += u;
      s2 += u * u;
    }
#pragma unroll
  for (int off = 32; off >= 1; off >>= 1) {
    s += __shfl_xor(s, off, 64);
    s2 += __shfl_xor(s2, off, 64);
  }
  float mu = s * (1.0f / kH);
  float var = s2 * (1.0f / kH) - mu * mu;
  float rs = rsqrtf(var + 1e-5f);
  int c0 = lane * 16;
#pragma unroll
  for (int j = 0; j < 4; ++j) {
    f32x4 gg = *(const f32x4*)(g + c0 + j * 4);
    f32x4 bb = *(const f32x4*)(b + c0 + j * 4);
    f32x4 o;
#pragma unroll
    for (int t = 0; t < 4; ++t) o[t] = (v[j][t] - mu) * rs * gg[t] + bb[t];
    *(f32x4*)(out + base + j * 4) = o;
  }
}

extern "C" void kernel_launch(void* const* d_in, const int* in_sizes, int n_in,
                              void* d_out, int out_size, void* d_ws, size_t ws_size,
                              hipStream_t stream) {
  const float* x = (const float*)d_in[0];
  const float* We1 = (const float*)d_in[1];
  const float* be1 = (const float*)d_in[2];
  const float* We2 = (const float*)d_in[3];
  const float* be2 = (const float*)d_in[4];
  const float* Wq = (const float*)d_in[5];
  const float* bq = (const float*)d_in[6];
  const float* Wk = (const float*)d_in[7];
  const float* bk = (const float*)d_in[8];
  const float* Wv = (const float*)d_in[9];
  const float* bv = (const float*)d_in[10];
  const float* ln_g = (const float*)d_in[11];
  const float* ln_b = (const float*)d_in[12];
  const int* curp = (const int*)d_in[13];
  float* out = (float*)d_out;

  char* ws = (char*)d_ws;
  const size_t MB = 1ull << 20;
  // Fixed base layout (342 MB):
  bf16_t* stacked = (bf16_t*)(ws);             // [E][M][H] 256MB
  bf16_t* xb = (bf16_t*)(ws + 256 * MB);       // [M][H]    32MB
  bf16_t* boostb = (bf16_t*)(ws + 288 * MB);   // [M][H]    32MB
  bf16_t* wA = (bf16_t*)(ws + 320 * MB);       // [DH][H]    8MB (per-expert We1^T)
  bf16_t* wB = (bf16_t*)(ws + 328 * MB);       // [H][DH]    8MB (per-expert We2^T)
  bf16_t* WqT = (bf16_t*)(ws + 336 * MB);      // 2MB
  bf16_t* WkC = (bf16_t*)(ws + 338 * MB);      // 2MB
  bf16_t* WvT = (bf16_t*)(ws + 340 * MB);      // 2MB
  char* dyn = ws + 342 * MB;
  size_t rem = ws_size > 342 * MB ? ws_size - 342 * MB : 0;
  int nchunk;
  bool f32boost;
  if (rem >= 192 * MB) { nchunk = 1; f32boost = true; }
  else if (rem >= 128 * MB) { nchunk = 1; f32boost = false; }
  else if (rem >= 64 * MB) { nchunk = 2; f32boost = false; }
  else { nchunk = 4; f32boost = false; }
  bf16_t* hbuf = (bf16_t*)dyn;
  float* boostf = (float*)(dyn + 128 * MB);
  bf16_t* qb_ = hbuf;            // 32MB  (h dead)
  bf16_t* qkb = boostb;          // 32MB  (boost dead)
  bf16_t* mixb = xb;             // 32MB  (xb dead after q GEMM)
  float* yf = (float*)ws;        // 64MB  (stacked dead after scores_mix)

  const int Mc = kM / nchunk;
  const size_t MH = (size_t)kM * kH;
  const u32 kLds = 163840;
  dim3 blk(256), blk5(512);

  cvt_flat_kernel<<<(kM * kH) / 1024, blk, 0, stream>>>(x, xb, (kM * kH) / 4);
  cvt_flat_kernel<<<(kH * kH) / 1024, blk, 0, stream>>>(Wk, WkC, (kH * kH) / 4);
  transpose_cvt_kernel<<<dim3(kH / 32, kH / 32), blk, 0, stream>>>(Wq, WqT, kH, kH);
  transpose_cvt_kernel<<<dim3(kH / 32, kH / 32), blk, 0, stream>>>(Wv, WvT, kH, kH);

  for (int i = 0; i < kE; ++i) {
    transpose_cvt_kernel<<<dim3(kDH / 32, kH / 32), blk, 0, stream>>>(
        We1 + (size_t)i * kH * kDH, wA, kH, kDH);
    transpose_cvt_kernel<<<dim3(kH / 32, kDH / 32), blk, 0, stream>>>(
        We2 + (size_t)i * kH * kDH, wB, kDH, kH);
    for (int c = 0; c < nchunk; ++c) {
      const size_t ro = (size_t)c * Mc * kH;
      const bf16_t* Ain = ((i == 0) ? xb : boostb) + ro;
      {
        int nwg = (Mc / 256) * (kDH / 256);
        gemm256_kernel<0><<<nwg, blk5, kLds, stream>>>(
            Ain, wA, Mc, kDH, kH, nwg, be1 + (size_t)i * kDH, hbuf,
            nullptr, nullptr, nullptr, nullptr, nullptr, nullptr, nullptr, curp, i);
      }
      int nwg = (Mc / 256) * (kH / 256);
      if (f32boost) {
        const float* bin = ((i == 0) ? x : boostf) + ro;
        gemm256_kernel<1><<<nwg, blk5, kLds, stream>>>(
            hbuf, wB, Mc, kH, kDH, nwg, be2 + (size_t)i * kH, nullptr,
            bin, boostf + ro, nullptr, boostb + ro, stacked + (size_t)i * MH + ro,
            nullptr, nullptr, curp, i);
      } else {
        const bf16_t* binb = ((i == 0) ? xb : boostb) + ro;
        gemm256_kernel<4><<<nwg, blk5, kLds, stream>>>(
            hbuf, wB, Mc, kH, kDH, nwg, be2 + (size_t)i * kH, nullptr,
            nullptr, nullptr, binb, boostb + ro, stacked + (size_t)i * MH + ro,
            nullptr, nullptr, curp, i);
      }
    }
  }

  const int nwgH = (kM / 256) * (kH / 256);
  // q = x Wq + bq
  gemm256_kernel<2><<<nwgH, blk5, kLds, stream>>>(
      xb, WqT, kM, kH, kH, nwgH, bq, qb_,
      nullptr, nullptr, nullptr, nullptr, nullptr, nullptr, nullptr, curp, 0);
  // qk[m,h] = sum_d q[m,d] * Wk[h,d]
  gemm256_kernel<2><<<nwgH, blk5, kLds, stream>>>(
      qb_, WkC, kM, kH, kH, nwgH, nullptr, qkb,
      nullptr, nullptr, nullptr, nullptr, nullptr, nullptr, nullptr, curp, 0);
  // scores -> softmax -> mix
  scores_mix_kernel<<<dim3(kM / 4), blk, 0, stream>>>(qkb, qb_, bk, stacked, mixb, curp);
  // y = x + mix Wv + bv
  gemm256_kernel<3><<<nwgH, blk5, kLds, stream>>>(
      mixb, WvT, kM, kH, kH, nwgH, bv, nullptr,
      nullptr, nullptr, nullptr, nullptr, nullptr, x, yf, curp, 0);
  // LayerNorm
  layernorm_kernel<<<dim3(kM / 4), blk, 0, stream>>>(yf, ln_g, ln_b, out);
}

// Round 11
// 2906.430 us; speedup vs baseline: 1.1911x; 1.1911x over previous
//
#include <hip/hip_runtime.h>
#include <math.h>

typedef __bf16 bf16_t;
typedef __bf16 bf16x8 __attribute__((ext_vector_type(8)));
typedef __bf16 bf16x4 __attribute__((ext_vector_type(4)));
typedef float f32x4 __attribute__((ext_vector_type(4)));
typedef unsigned int u32;
typedef unsigned short u16;

static constexpr int kBd = 8, kS = 2048, kH = 1024, kDH = 4096, kE = 8;
static constexpr int kM = kBd * kS;        // 16384 rows
static constexpr float kScale = 0.03125f;  // 1/sqrt(1024)

__device__ __forceinline__ void gload_lds16(const void* g, void* l) {
  __builtin_amdgcn_global_load_lds(
      (const __attribute__((address_space(1))) u32*)g,
      (__attribute__((address_space(3))) u32*)l, 16, 0, 0);
}

// ---------------- conversion kernels ----------------
__global__ __launch_bounds__(256) void cvt_flat_kernel(const float* __restrict__ in,
                                                       bf16_t* __restrict__ out, int n4) {
  int i = blockIdx.x * 256 + threadIdx.x;
  if (i >= n4) return;
  f32x4 v = *(const f32x4*)(in + (size_t)i * 4);
  bf16x4 o;
#pragma unroll
  for (int j = 0; j < 4; ++j) o[j] = (bf16_t)v[j];
  *(bf16x4*)(out + (size_t)i * 4) = o;
}

// out[c][r] = bf16(in[r][c]); grid (C/32, R/32)
__global__ __launch_bounds__(256) void transpose_cvt_kernel(
    const float* __restrict__ in, bf16_t* __restrict__ out, int R, int C) {
  __shared__ float tile[32][33];
  int tx = threadIdx.x & 31, ty = threadIdx.x >> 5;  // 32 x 8
  int c0 = blockIdx.x * 32, r0 = blockIdx.y * 32;
#pragma unroll
  for (int yy = 0; yy < 4; ++yy)
    tile[ty + yy * 8][tx] = in[(size_t)(r0 + ty + yy * 8) * C + c0 + tx];
  __syncthreads();
#pragma unroll
  for (int yy = 0; yy < 4; ++yy)
    out[(size_t)(c0 + ty + yy * 8) * R + r0 + tx] = (bf16_t)tile[tx][ty + yy * 8];
}

// ---- 256x256x64 GEMM, overlap schedule (round-9 core): Bt = B^T [N,K] ----
// LDS 160KB: A triple-buf (3x32KB, buf=t%3) + B dbuf (2x32KB, buf=t&1).
// 16x16x32 MFMA; issue-early ds_reads, compiler counted waits; 1 barrier +
// counted vmcnt(8) gate per tile (vmcnt(0) tail).
// MODE 0: outb = bf16(relu(acc+bias))
// MODE 2: outb = bf16(acc+bias)
// MODE 3: yout = acc + bias + xres   (f32)
// MODE 4: eo = acc+bias; nb = (float)bin_b + 0.5*eo; bout_b = bf16(nb);
//         stacked = bf16(eo) [nontemporal — read only much later]
template <int MODE>
__global__ __launch_bounds__(512, 2) void gemm256_kernel(
    const bf16_t* __restrict__ A, const bf16_t* __restrict__ Bt,
    int M, int N, int K, int nwg,
    const float* __restrict__ bias,
    bf16_t* __restrict__ outb,
    const bf16_t* __restrict__ bin_b, bf16_t* __restrict__ bout_b,
    bf16_t* __restrict__ stacked,
    const float* __restrict__ xres, float* __restrict__ yout,
    const int* __restrict__ curp, int expert_i) {
  if ((MODE == 0 || MODE == 4) && expert_i > *curp) return;
  extern __shared__ char lds_buf[];           // 163840 bytes
  char* Abase = lds_buf;                      // 3 x 32KB
  char* Bbase = lds_buf + 98304;              // 2 x 32KB
  const int tid = threadIdx.x;
  const int lane = tid & 63, wid = tid >> 6;
  const int wr = wid >> 2, wc = wid & 3;      // 2(M) x 4(N) waves; 128x64 per wave
  const int fr = lane & 15, fh = lane >> 4;   // frag row / k-group
  const int lane_swz = (fr * 64 + fh * 16) ^ ((fr >> 3) << 5);
  // bijective XCD swizzle (all grids here are %8==0)
  const int bid = blockIdx.x;
  const int wg = (bid & 7) * (nwg >> 3) + (bid >> 3);
  const int nMb = M >> 8;
  const int m0 = (wg % nMb) << 8, n0 = (wg / nMb) << 8;
  // staging map: thread covers 16B chunks q=tid and q=tid+512 of each 16KB half
  int grow[2], gcol[2];
#pragma unroll
  for (int j = 0; j < 2; ++j) {
    int L = (j * 512 + tid) * 16;
    int Lp = L ^ (((L >> 9) & 1) << 5);  // inverse st swizzle on source
    int s = Lp >> 10;
    grow[j] = ((s >> 1) << 4) + ((Lp >> 6) & 15);
    gcol[j] = ((s & 1) << 5) + (((Lp >> 4) & 3) << 3);
  }
  const bf16_t* sA[2] = {A + (size_t)(m0 + grow[0]) * K + gcol[0],
                         A + (size_t)(m0 + grow[1]) * K + gcol[1]};
  const bf16_t* sB[2] = {Bt + (size_t)(n0 + grow[0]) * K + gcol[0],
                         Bt + (size_t)(n0 + grow[1]) * K + gcol[1]};
  const size_t rstep = (size_t)128 * K;

#define STAGE(SP, BASE, tau, h)                                               \
  {                                                                           \
    char* d_ = (BASE) + ((h) << 14) + (wid << 10);                            \
    gload_lds16(SP[0] + (size_t)(h)*rstep + (size_t)(tau)*64, d_);            \
    gload_lds16(SP[1] + (size_t)(h)*rstep + (size_t)(tau)*64, d_ + 8192);     \
  }
#define STAGE_A(buf, t, h) STAGE(sA, Abase + (buf)*32768, (t), (h))
#define STAGE_B(t, h) STAGE(sB, Bbase + (((t)&1) << 15), (t), (h))
#define SB0() __builtin_amdgcn_sched_barrier(0)

  const int bq = (wc & 1) * 4;  // B rowblk base within half

  f32x4 acc[8][4] = {};
  const int NT = K >> 6;  // K/64, >= 16 here

// quad p MFMA: rows 2p,2p+1 of acc; A-frags af[0..3] (bytes [4p,4p+4)KB)
#define QUAD(p, af)                                                            \
  __builtin_amdgcn_s_setprio(1);                                               \
  _Pragma("unroll") for (int nf = 0; nf < 4; ++nf) {                           \
    acc[2 * (p)][nf] = __builtin_amdgcn_mfma_f32_16x16x32_bf16(                \
        af[0], b[nf][0], acc[2 * (p)][nf], 0, 0, 0);                           \
    acc[2 * (p)][nf] = __builtin_amdgcn_mfma_f32_16x16x32_bf16(                \
        af[1], b[nf][1], acc[2 * (p)][nf], 0, 0, 0);                           \
    acc[2 * (p) + 1][nf] = __builtin_amdgcn_mfma_f32_16x16x32_bf16(            \
        af[2], b[nf][0], acc[2 * (p) + 1][nf], 0, 0, 0);                       \
    acc[2 * (p) + 1][nf] = __builtin_amdgcn_mfma_f32_16x16x32_bf16(            \
        af[3], b[nf][1], acc[2 * (p) + 1][nf], 0, 0, 0);                       \
  }                                                                            \
  __builtin_amdgcn_s_setprio(0);

  // prologue: A(0),B(0),A(1),B(1); leave A(1),B(1) (8 loads) in flight
  STAGE_A(0, 0, 0); STAGE_A(0, 0, 1);
  STAGE_B(0, 0); STAGE_B(0, 1);
  STAGE_A(1, 1, 0); STAGE_A(1, 1, 1);
  STAGE_B(1, 0); STAGE_B(1, 1);
  asm volatile("s_waitcnt vmcnt(8)" ::: "memory");
  __builtin_amdgcn_s_barrier();

  int am0 = 0;
  for (int t = 0; t < NT; ++t) {
    int am2 = am0 + 2; if (am2 >= 3) am2 -= 3;
    const char* Ar = Abase + am0 * 32768 + (wr << 14) + lane_swz;
    const char* Br = Bbase + ((t & 1) << 15) + ((wc >> 1) << 14) + lane_swz;
    bf16x8 b[4][2], a01[8], a23[8];
    const bool st = (t + 2 < NT);
    // --- group 1: B reads (FIFO-first, needed for the in-place B restage) ---
#pragma unroll
    for (int nf = 0; nf < 4; ++nf)
#pragma unroll
      for (int kk = 0; kk < 2; ++kk)
        b[nf][kk] = *(const bf16x8*)(Br + ((bq + nf) * 2 + kk) * 1024);
    SB0();
    // --- group 2: A quads 0-1 ---
#pragma unroll
    for (int i = 0; i < 8; ++i) a01[i] = *(const bf16x8*)(Ar + i * 1024);
    SB0();
    // --- stage A(t+2) into disjoint buffer am2 ---
    if (st) { STAGE_A(am2, t + 2, 0); STAGE_A(am2, t + 2, 1); }
    SB0();
    // --- quad0 (compiler waits only for b + a01[0..3]); a23 issue floats here ---
    QUAD(0, (&a01[0]));
#pragma unroll
    for (int i = 0; i < 8; ++i) a23[i] = *(const bf16x8*)(Ar + (8 + i) * 1024);
    SB0();
    QUAD(1, (&a01[4]));
    // --- formal fence: B reads (first 8 in FIFO) drained; restage B in place ---
    asm volatile("s_waitcnt lgkmcnt(8)" ::: "memory");
    SB0();
    if (st) { STAGE_B(t + 2, 0); STAGE_B(t + 2, 1); }
    SB0();
    QUAD(2, (&a23[0]));
    QUAD(3, (&a23[4]));
    // --- counted gate: drains stages of tile t-1 (what tile t+1 reads) ---
    if (t < NT - 2) {
      asm volatile("s_waitcnt vmcnt(8)" ::: "memory");
    } else {
      asm volatile("s_waitcnt vmcnt(0)" ::: "memory");
    }
    __builtin_amdgcn_s_barrier();
    am0 = am0 + 1; if (am0 >= 3) am0 -= 3;
  }
#undef QUAD
#undef STAGE
#undef STAGE_A
#undef STAGE_B
#undef SB0

  // ---- epilogue ----
#pragma unroll
  for (int nf = 0; nf < 4; ++nf) {
    const int col = n0 + wc * 64 + nf * 16 + fr;
    const float bv = bias ? bias[col] : 0.0f;
#pragma unroll
    for (int mf = 0; mf < 8; ++mf) {
#pragma unroll
      for (int r = 0; r < 4; ++r) {
        const int row = m0 + wr * 128 + mf * 16 + fh * 4 + r;
        const size_t idx = (size_t)row * N + col;
        float v = acc[mf][nf][r] + bv;
        if (MODE == 0) {
          outb[idx] = (bf16_t)(v > 0.0f ? v : 0.0f);
        } else if (MODE == 2) {
          outb[idx] = (bf16_t)v;
        } else if (MODE == 4) {
          float nb2 = (float)bin_b[idx] + 0.5f * v;
          bout_b[idx] = (bf16_t)nb2;
          __builtin_nontemporal_store((bf16_t)v, &stacked[idx]);
        } else {
          yout[idx] = v + xres[idx];
        }
      }
    }
  }
}

// ---------------- scores + softmax + mix ----------------
__global__ __launch_bounds__(256) void scores_mix_kernel(
    const bf16_t* __restrict__ qk, const bf16_t* __restrict__ q,
    const float* __restrict__ bk, const bf16_t* __restrict__ stacked,
    bf16_t* __restrict__ mix, const int* __restrict__ curp) {
  const int n = *curp + 1;
  int lane = threadIdx.x & 63, wave = threadIdx.x >> 6;
  int m = blockIdx.x * 4 + wave;
  size_t base = (size_t)m * kH + lane * 16;
  int c0 = lane * 16;
  bf16x8 qk0 = *(const bf16x8*)(qk + base);
  bf16x8 qk1 = *(const bf16x8*)(qk + base + 8);
  bf16x8 q0 = *(const bf16x8*)(q + base);
  bf16x8 q1 = *(const bf16x8*)(q + base + 8);
  float sc[kE + 1];
  bf16x8 eo0[kE], eo1[kE];
#pragma unroll
  for (int e = 0; e < kE; ++e) {
    sc[e] = 0.0f;
    if (e < n) {
      size_t sb = (size_t)e * kM * kH + base;
      eo0[e] = *(const bf16x8*)(stacked + sb);
      eo1[e] = *(const bf16x8*)(stacked + sb + 8);
      float d = 0.0f;
#pragma unroll
      for (int j = 0; j < 8; ++j)
        d += (float)eo0[e][j] * (float)qk0[j] + (float)eo1[e][j] * (float)qk1[j];
      sc[e] = d;
    }
  }
  {
    float qb = 0.0f;
#pragma unroll
    for (int j = 0; j < 8; ++j)
      qb += (float)q0[j] * bk[c0 + j] + (float)q1[j] * bk[c0 + 8 + j];
    sc[kE] = qb;
  }
#pragma unroll
  for (int off = 32; off >= 1; off >>= 1)
#pragma unroll
    for (int e = 0; e <= kE; ++e) sc[e] += __shfl_xor(sc[e], off, 64);
  float s[kE];
  float mx = -1e30f;
#pragma unroll
  for (int e = 0; e < kE; ++e)
    if (e < n) {
      s[e] = (sc[e] + sc[kE]) * kScale;
      mx = fmaxf(mx, s[e]);
    }
  float Z = 0.0f;
#pragma unroll
  for (int e = 0; e < kE; ++e)
    if (e < n) {
      s[e] = expf(s[e] - mx);
      Z += s[e];
    }
  float inv = 1.0f / Z;
  float mv[16];
#pragma unroll
  for (int j = 0; j < 16; ++j) mv[j] = 0.0f;
#pragma unroll
  for (int e = 0; e < kE; ++e)
    if (e < n) {
      float w = s[e] * inv;
#pragma unroll
      for (int j = 0; j < 8; ++j) {
        mv[j] += w * (float)eo0[e][j];
        mv[8 + j] += w * (float)eo1[e][j];
      }
    }
  bf16x8 o0, o1;
#pragma unroll
  for (int j = 0; j < 8; ++j) {
    o0[j] = (bf16_t)mv[j];
    o1[j] = (bf16_t)mv[8 + j];
  }
  *(bf16x8*)(mix + base) = o0;
  *(bf16x8*)(mix + base + 8) = o1;
}

// ---------------- LayerNorm ----------------
__global__ __launch_bounds__(256) void layernorm_kernel(
    const float* __restrict__ y, const float* __restrict__ g,
    const float* __restrict__ b, float* __restrict__ out) {
  int lane = threadIdx.x & 63, wave = threadIdx.x >> 6;
  int m = blockIdx.x * 4 + wave;
  size_t base = (size_t)m * kH + lane * 16;
  f32x4 v[4];
#pragma unroll
  for (int j = 0; j < 4; ++j) v[j] = *(const f32x4*)(y + base + j * 4);
  float s = 0.0f, s2 = 0.0f;
#pragma unroll
  for (int j = 0; j < 4; ++j)
#pragma unroll
    for (int t = 0; t < 4; ++t) {
      float u = v[j][t];
      s += u;
      s2 += u * u;
    }
#pragma unroll
  for (int off = 32; off >= 1; off >>= 1) {
    s += __shfl_xor(s, off, 64);
    s2 += __shfl_xor(s2, off, 64);
  }
  float mu = s * (1.0f / kH);
  float var = s2 * (1.0f / kH) - mu * mu;
  float rs = rsqrtf(var + 1e-5f);
  int c0 = lane * 16;
#pragma unroll
  for (int j = 0; j < 4; ++j) {
    f32x4 gg = *(const f32x4*)(g + c0 + j * 4);
    f32x4 bb = *(const f32x4*)(b + c0 + j * 4);
    f32x4 o;
#pragma unroll
    for (int t = 0; t < 4; ++t) o[t] = (v[j][t] - mu) * rs * gg[t] + bb[t];
    *(f32x4*)(out + base + j * 4) = o;
  }
}

extern "C" void kernel_launch(void* const* d_in, const int* in_sizes, int n_in,
                              void* d_out, int out_size, void* d_ws, size_t ws_size,
                              hipStream_t stream) {
  const float* x = (const float*)d_in[0];
  const float* We1 = (const float*)d_in[1];
  const float* be1 = (const float*)d_in[2];
  const float* We2 = (const float*)d_in[3];
  const float* be2 = (const float*)d_in[4];
  const float* Wq = (const float*)d_in[5];
  const float* bq = (const float*)d_in[6];
  const float* Wk = (const float*)d_in[7];
  const float* bk = (const float*)d_in[8];
  const float* Wv = (const float*)d_in[9];
  const float* bv = (const float*)d_in[10];
  const float* ln_g = (const float*)d_in[11];
  const float* ln_b = (const float*)d_in[12];
  const int* curp = (const int*)d_in[13];
  float* out = (float*)d_out;

  char* ws = (char*)d_ws;
  const size_t MB = 1ull << 20;
  // Fixed base layout (342 MB):
  bf16_t* stacked = (bf16_t*)(ws);             // [E][M][H] 256MB
  bf16_t* xb = (bf16_t*)(ws + 256 * MB);       // [M][H]    32MB
  bf16_t* boostb = (bf16_t*)(ws + 288 * MB);   // [M][H]    32MB
  bf16_t* wA = (bf16_t*)(ws + 320 * MB);       // [DH][H]    8MB (per-expert We1^T)
  bf16_t* wB = (bf16_t*)(ws + 328 * MB);       // [H][DH]    8MB (per-expert We2^T)
  bf16_t* WqT = (bf16_t*)(ws + 336 * MB);      // 2MB
  bf16_t* WkC = (bf16_t*)(ws + 338 * MB);      // 2MB
  bf16_t* WvT = (bf16_t*)(ws + 340 * MB);      // 2MB
  char* dyn = ws + 342 * MB;
  size_t rem = ws_size > 342 * MB ? ws_size - 342 * MB : 0;
  int nchunk;
  if (rem >= 128 * MB) nchunk = 1;        // h 128MB
  else if (rem >= 64 * MB) nchunk = 2;    // h 64MB
  else nchunk = 4;                        // h 32MB (floor 374MB)
  bf16_t* hbuf = (bf16_t*)dyn;
  bf16_t* qb_ = hbuf;            // 32MB  (h dead)
  bf16_t* qkb = boostb;          // 32MB  (boost dead)
  bf16_t* mixb = xb;             // 32MB  (xb dead after q GEMM)
  float* yf = (float*)ws;        // 64MB  (stacked dead after scores_mix)

  const int Mc = kM / nchunk;
  const size_t MH = (size_t)kM * kH;
  const u32 kLds = 163840;
  dim3 blk(256), blk5(512);

  cvt_flat_kernel<<<(kM * kH) / 1024, blk, 0, stream>>>(x, xb, (kM * kH) / 4);
  cvt_flat_kernel<<<(kH * kH) / 1024, blk, 0, stream>>>(Wk, WkC, (kH * kH) / 4);
  transpose_cvt_kernel<<<dim3(kH / 32, kH / 32), blk, 0, stream>>>(Wq, WqT, kH, kH);
  transpose_cvt_kernel<<<dim3(kH / 32, kH / 32), blk, 0, stream>>>(Wv, WvT, kH, kH);

  for (int i = 0; i < kE; ++i) {
    transpose_cvt_kernel<<<dim3(kDH / 32, kH / 32), blk, 0, stream>>>(
        We1 + (size_t)i * kH * kDH, wA, kH, kDH);
    transpose_cvt_kernel<<<dim3(kH / 32, kDH / 32), blk, 0, stream>>>(
        We2 + (size_t)i * kH * kDH, wB, kDH, kH);
    for (int c = 0; c < nchunk; ++c) {
      const size_t ro = (size_t)c * Mc * kH;
      const bf16_t* Ain = ((i == 0) ? xb : boostb) + ro;
      {
        int nwg = (Mc / 256) * (kDH / 256);
        gemm256_kernel<0><<<nwg, blk5, kLds, stream>>>(
            Ain, wA, Mc, kDH, kH, nwg, be1 + (size_t)i * kDH, hbuf,
            nullptr, nullptr, nullptr, nullptr, nullptr, curp, i);
      }
      int nwg = (Mc / 256) * (kH / 256);
      const bf16_t* binb = ((i == 0) ? xb : boostb) + ro;
      gemm256_kernel<4><<<nwg, blk5, kLds, stream>>>(
          hbuf, wB, Mc, kH, kDH, nwg, be2 + (size_t)i * kH, nullptr,
          binb, boostb + ro, stacked + (size_t)i * MH + ro,
          nullptr, nullptr, curp, i);
    }
  }

  const int nwgH = (kM / 256) * (kH / 256);
  // q = x Wq + bq
  gemm256_kernel<2><<<nwgH, blk5, kLds, stream>>>(
      xb, WqT, kM, kH, kH, nwgH, bq, qb_,
      nullptr, nullptr, nullptr, nullptr, nullptr, curp, 0);
  // qk[m,h] = sum_d q[m,d] * Wk[h,d]
  gemm256_kernel<2><<<nwgH, blk5, kLds, stream>>>(
      qb_, WkC, kM, kH, kH, nwgH, nullptr, qkb,
      nullptr, nullptr, nullptr, nullptr, nullptr, curp, 0);
  // scores -> softmax -> mix
  scores_mix_kernel<<<dim3(kM / 4), blk, 0, stream>>>(qkb, qb_, bk, stacked, mixb, curp);
  // y = x + mix Wv + bv
  gemm256_kernel<3><<<nwgH, blk5, kLds, stream>>>(
      mixb, WvT, kM, kH, kH, nwgH, bv, nullptr,
      nullptr, nullptr, nullptr, x, yf, curp, 0);
  // LayerNorm
  layernorm_kernel<<<dim3(kM / 4), blk, 0, stream>>>(yf, ln_g, ln_b, out);
}

// Round 12
// 2849.650 us; speedup vs baseline: 1.2148x; 1.0199x over previous
//
#include <hip/hip_runtime.h>
#include <math.h>

typedef __bf16 bf16_t;
typedef __bf16 bf16x8 __attribute__((ext_vector_type(8)));
typedef __bf16 bf16x4 __attribute__((ext_vector_type(4)));
typedef float f32x4 __attribute__((ext_vector_type(4)));
typedef unsigned int u32;

static constexpr int kBd = 8, kS = 2048, kH = 1024, kDH = 4096, kE = 8;
static constexpr int kM = kBd * kS;        // 16384 rows
static constexpr float kScale = 0.03125f;  // 1/sqrt(1024)

__device__ __forceinline__ void gload_lds16(const void* g, void* l) {
  __builtin_amdgcn_global_load_lds(
      (const __attribute__((address_space(1))) u32*)g,
      (__attribute__((address_space(3))) u32*)l, 16, 0, 0);
}

// ---------------- conversion kernels ----------------
__global__ __launch_bounds__(256) void cvt_flat_kernel(const float* __restrict__ in,
                                                       bf16_t* __restrict__ out, int n4) {
  int i = blockIdx.x * 256 + threadIdx.x;
  if (i >= n4) return;
  f32x4 v = *(const f32x4*)(in + (size_t)i * 4);
  bf16x4 o;
#pragma unroll
  for (int j = 0; j < 4; ++j) o[j] = (bf16_t)v[j];
  *(bf16x4*)(out + (size_t)i * 4) = o;
}

// out[c][r] = bf16(in[r][c]); grid (C/32, R/32)
__global__ __launch_bounds__(256) void transpose_cvt_kernel(
    const float* __restrict__ in, bf16_t* __restrict__ out, int R, int C) {
  __shared__ float tile[32][33];
  int tx = threadIdx.x & 31, ty = threadIdx.x >> 5;  // 32 x 8
  int c0 = blockIdx.x * 32, r0 = blockIdx.y * 32;
#pragma unroll
  for (int yy = 0; yy < 4; ++yy)
    tile[ty + yy * 8][tx] = in[(size_t)(r0 + ty + yy * 8) * C + c0 + tx];
  __syncthreads();
#pragma unroll
  for (int yy = 0; yy < 4; ++yy)
    out[(size_t)(c0 + ty + yy * 8) * R + r0 + tx] = (bf16_t)tile[tx][ty + yy * 8];
}

// ---- 256x256x64 GEMM, overlap schedule (round-9 core): Bt = B^T [N,K] ----
// LDS 160KB: A triple-buf (3x32KB, buf=t%3) + B dbuf (2x32KB, buf=t&1).
// 16x16x32 MFMA; issue-early ds_reads, compiler counted waits; 1 barrier +
// counted vmcnt(8) gate per tile (vmcnt(0) tail).
// Grid mapping: locality chunks of 8 m-blocks x all n-blocks, composed with
// the bijective XCD swizzle -> each XCD owns whole chunks (A-chunk ~4MB
// L2-resident across its n-sweep; cuts HBM re-fetch).
// MODE 0: outb = bf16(relu(acc+bias))
// MODE 2: outb = bf16(acc+bias)
// MODE 3: yout = acc + bias + xres   (f32)
// MODE 4: eo = acc+bias; nb = (float)bin_b + 0.5*eo; bout_b = bf16(nb); stacked = bf16(eo)
template <int MODE>
__global__ __launch_bounds__(512, 2) void gemm256_kernel(
    const bf16_t* __restrict__ A, const bf16_t* __restrict__ Bt,
    int M, int N, int K, int nwg,
    const float* __restrict__ bias,
    bf16_t* __restrict__ outb,
    const bf16_t* __restrict__ bin_b, bf16_t* __restrict__ bout_b,
    bf16_t* __restrict__ stacked,
    const float* __restrict__ xres, float* __restrict__ yout,
    const int* __restrict__ curp, int expert_i) {
  if ((MODE == 0 || MODE == 4) && expert_i > *curp) return;
  extern __shared__ char lds_buf[];           // 163840 bytes
  char* Abase = lds_buf;                      // 3 x 32KB
  char* Bbase = lds_buf + 98304;              // 2 x 32KB
  const int tid = threadIdx.x;
  const int lane = tid & 63, wid = tid >> 6;
  const int wr = wid >> 2, wc = wid & 3;      // 2(M) x 4(N) waves; 128x64 per wave
  const int fr = lane & 15, fh = lane >> 4;   // frag row / k-group
  const int lane_swz = (fr * 64 + fh * 16) ^ ((fr >> 3) << 5);
  // bijective XCD swizzle (all grids here are %8==0) + locality chunking
  const int bid = blockIdx.x;
  const int wg = (bid & 7) * (nwg >> 3) + (bid >> 3);
  const int nNb = N >> 8;
  const int chsz = 8 * nNb;
  const int chunk = wg / chsz, loc = wg % chsz;
  const int m0 = (chunk * 8 + (loc & 7)) << 8;
  const int n0 = (loc >> 3) << 8;
  // staging map: thread covers 16B chunks q=tid and q=tid+512 of each 16KB half
  int grow[2], gcol[2];
#pragma unroll
  for (int j = 0; j < 2; ++j) {
    int L = (j * 512 + tid) * 16;
    int Lp = L ^ (((L >> 9) & 1) << 5);  // inverse st swizzle on source
    int s = Lp >> 10;
    grow[j] = ((s >> 1) << 4) + ((Lp >> 6) & 15);
    gcol[j] = ((s & 1) << 5) + (((Lp >> 4) & 3) << 3);
  }
  const bf16_t* sA[2] = {A + (size_t)(m0 + grow[0]) * K + gcol[0],
                         A + (size_t)(m0 + grow[1]) * K + gcol[1]};
  const bf16_t* sB[2] = {Bt + (size_t)(n0 + grow[0]) * K + gcol[0],
                         Bt + (size_t)(n0 + grow[1]) * K + gcol[1]};
  const size_t rstep = (size_t)128 * K;

#define STAGE(SP, BASE, tau, h)                                               \
  {                                                                           \
    char* d_ = (BASE) + ((h) << 14) + (wid << 10);                            \
    gload_lds16(SP[0] + (size_t)(h)*rstep + (size_t)(tau)*64, d_);            \
    gload_lds16(SP[1] + (size_t)(h)*rstep + (size_t)(tau)*64, d_ + 8192);     \
  }
#define STAGE_A(buf, t, h) STAGE(sA, Abase + (buf)*32768, (t), (h))
#define STAGE_B(t, h) STAGE(sB, Bbase + (((t)&1) << 15), (t), (h))
#define SB0() __builtin_amdgcn_sched_barrier(0)

  const int bq = (wc & 1) * 4;  // B rowblk base within half

  f32x4 acc[8][4] = {};
  const int NT = K >> 6;  // K/64, >= 16 here

// quad p MFMA: rows 2p,2p+1 of acc; A-frags af[0..3] (bytes [4p,4p+4)KB)
#define QUAD(p, af)                                                            \
  __builtin_amdgcn_s_setprio(1);                                               \
  _Pragma("unroll") for (int nf = 0; nf < 4; ++nf) {                           \
    acc[2 * (p)][nf] = __builtin_amdgcn_mfma_f32_16x16x32_bf16(                \
        af[0], b[nf][0], acc[2 * (p)][nf], 0, 0, 0);                           \
    acc[2 * (p)][nf] = __builtin_amdgcn_mfma_f32_16x16x32_bf16(                \
        af[1], b[nf][1], acc[2 * (p)][nf], 0, 0, 0);                           \
    acc[2 * (p) + 1][nf] = __builtin_amdgcn_mfma_f32_16x16x32_bf16(            \
        af[2], b[nf][0], acc[2 * (p) + 1][nf], 0, 0, 0);                       \
    acc[2 * (p) + 1][nf] = __builtin_amdgcn_mfma_f32_16x16x32_bf16(            \
        af[3], b[nf][1], acc[2 * (p) + 1][nf], 0, 0, 0);                       \
  }                                                                            \
  __builtin_amdgcn_s_setprio(0);

  // prologue: A(0),B(0),A(1),B(1); leave A(1),B(1) (8 loads) in flight
  STAGE_A(0, 0, 0); STAGE_A(0, 0, 1);
  STAGE_B(0, 0); STAGE_B(0, 1);
  STAGE_A(1, 1, 0); STAGE_A(1, 1, 1);
  STAGE_B(1, 0); STAGE_B(1, 1);
  asm volatile("s_waitcnt vmcnt(8)" ::: "memory");
  __builtin_amdgcn_s_barrier();

  int am0 = 0;
  for (int t = 0; t < NT; ++t) {
    int am2 = am0 + 2; if (am2 >= 3) am2 -= 3;
    const char* Ar = Abase + am0 * 32768 + (wr << 14) + lane_swz;
    const char* Br = Bbase + ((t & 1) << 15) + ((wc >> 1) << 14) + lane_swz;
    bf16x8 b[4][2], a01[8], a23[8];
    const bool st = (t + 2 < NT);
    // --- group 1: B reads (FIFO-first, needed for the in-place B restage) ---
#pragma unroll
    for (int nf = 0; nf < 4; ++nf)
#pragma unroll
      for (int kk = 0; kk < 2; ++kk)
        b[nf][kk] = *(const bf16x8*)(Br + ((bq + nf) * 2 + kk) * 1024);
    SB0();
    // --- group 2: A quads 0-1 ---
#pragma unroll
    for (int i = 0; i < 8; ++i) a01[i] = *(const bf16x8*)(Ar + i * 1024);
    SB0();
    // --- stage A(t+2) into disjoint buffer am2 ---
    if (st) { STAGE_A(am2, t + 2, 0); STAGE_A(am2, t + 2, 1); }
    SB0();
    // --- quad0 (compiler waits only for b + a01[0..3]); a23 issue floats here ---
    QUAD(0, (&a01[0]));
#pragma unroll
    for (int i = 0; i < 8; ++i) a23[i] = *(const bf16x8*)(Ar + (8 + i) * 1024);
    SB0();
    QUAD(1, (&a01[4]));
    // --- formal fence: B reads (first 8 in FIFO) drained; restage B in place ---
    asm volatile("s_waitcnt lgkmcnt(8)" ::: "memory");
    SB0();
    if (st) { STAGE_B(t + 2, 0); STAGE_B(t + 2, 1); }
    SB0();
    QUAD(2, (&a23[0]));
    QUAD(3, (&a23[4]));
    // --- counted gate: drains stages of tile t-1 (what tile t+1 reads) ---
    if (t < NT - 2) {
      asm volatile("s_waitcnt vmcnt(8)" ::: "memory");
    } else {
      asm volatile("s_waitcnt vmcnt(0)" ::: "memory");
    }
    __builtin_amdgcn_s_barrier();
    am0 = am0 + 1; if (am0 >= 3) am0 -= 3;
  }
#undef QUAD
#undef STAGE
#undef STAGE_A
#undef STAGE_B
#undef SB0

  // ---- epilogue ----
#pragma unroll
  for (int nf = 0; nf < 4; ++nf) {
    const int col = n0 + wc * 64 + nf * 16 + fr;
    const float bv = bias ? bias[col] : 0.0f;
#pragma unroll
    for (int mf = 0; mf < 8; ++mf) {
#pragma unroll
      for (int r = 0; r < 4; ++r) {
        const int row = m0 + wr * 128 + mf * 16 + fh * 4 + r;
        const size_t idx = (size_t)row * N + col;
        float v = acc[mf][nf][r] + bv;
        if (MODE == 0) {
          outb[idx] = (bf16_t)(v > 0.0f ? v : 0.0f);
        } else if (MODE == 2) {
          outb[idx] = (bf16_t)v;
        } else if (MODE == 4) {
          float nb2 = (float)bin_b[idx] + 0.5f * v;
          bout_b[idx] = (bf16_t)nb2;
          stacked[idx] = (bf16_t)v;
        } else {
          yout[idx] = v + xres[idx];
        }
      }
    }
  }
}

// ---------------- scores + softmax + mix ----------------
__global__ __launch_bounds__(256) void scores_mix_kernel(
    const bf16_t* __restrict__ qk, const bf16_t* __restrict__ q,
    const float* __restrict__ bk, const bf16_t* __restrict__ stacked,
    bf16_t* __restrict__ mix, const int* __restrict__ curp) {
  const int n = *curp + 1;
  int lane = threadIdx.x & 63, wave = threadIdx.x >> 6;
  int m = blockIdx.x * 4 + wave;
  size_t base = (size_t)m * kH + lane * 16;
  int c0 = lane * 16;
  bf16x8 qk0 = *(const bf16x8*)(qk + base);
  bf16x8 qk1 = *(const bf16x8*)(qk + base + 8);
  bf16x8 q0 = *(const bf16x8*)(q + base);
  bf16x8 q1 = *(const bf16x8*)(q + base + 8);
  float sc[kE + 1];
  bf16x8 eo0[kE], eo1[kE];
#pragma unroll
  for (int e = 0; e < kE; ++e) {
    sc[e] = 0.0f;
    if (e < n) {
      size_t sb = (size_t)e * kM * kH + base;
      eo0[e] = *(const bf16x8*)(stacked + sb);
      eo1[e] = *(const bf16x8*)(stacked + sb + 8);
      float d = 0.0f;
#pragma unroll
      for (int j = 0; j < 8; ++j)
        d += (float)eo0[e][j] * (float)qk0[j] + (float)eo1[e][j] * (float)qk1[j];
      sc[e] = d;
    }
  }
  {
    float qb = 0.0f;
#pragma unroll
    for (int j = 0; j < 8; ++j)
      qb += (float)q0[j] * bk[c0 + j] + (float)q1[j] * bk[c0 + 8 + j];
    sc[kE] = qb;
  }
#pragma unroll
  for (int off = 32; off >= 1; off >>= 1)
#pragma unroll
    for (int e = 0; e <= kE; ++e) sc[e] += __shfl_xor(sc[e], off, 64);
  float s[kE];
  float mx = -1e30f;
#pragma unroll
  for (int e = 0; e < kE; ++e)
    if (e < n) {
      s[e] = (sc[e] + sc[kE]) * kScale;
      mx = fmaxf(mx, s[e]);
    }
  float Z = 0.0f;
#pragma unroll
  for (int e = 0; e < kE; ++e)
    if (e < n) {
      s[e] = expf(s[e] - mx);
      Z += s[e];
    }
  float inv = 1.0f / Z;
  float mv[16];
#pragma unroll
  for (int j = 0; j < 16; ++j) mv[j] = 0.0f;
#pragma unroll
  for (int e = 0; e < kE; ++e)
    if (e < n) {
      float w = s[e] * inv;
#pragma unroll
      for (int j = 0; j < 8; ++j) {
        mv[j] += w * (float)eo0[e][j];
        mv[8 + j] += w * (float)eo1[e][j];
      }
    }
  bf16x8 o0, o1;
#pragma unroll
  for (int j = 0; j < 8; ++j) {
    o0[j] = (bf16_t)mv[j];
    o1[j] = (bf16_t)mv[8 + j];
  }
  *(bf16x8*)(mix + base) = o0;
  *(bf16x8*)(mix + base + 8) = o1;
}

// ---------------- LayerNorm ----------------
__global__ __launch_bounds__(256) void layernorm_kernel(
    const float* __restrict__ y, const float* __restrict__ g,
    const float* __restrict__ b, float* __restrict__ out) {
  int lane = threadIdx.x & 63, wave = threadIdx.x >> 6;
  int m = blockIdx.x * 4 + wave;
  size_t base = (size_t)m * kH + lane * 16;
  f32x4 v[4];
#pragma unroll
  for (int j = 0; j < 4; ++j) v[j] = *(const f32x4*)(y + base + j * 4);
  float s = 0.0f, s2 = 0.0f;
#pragma unroll
  for (int j = 0; j < 4; ++j)
#pragma unroll
    for (int t = 0; t < 4; ++t) {
      float u = v[j][t];
      s += u;
      s2 += u * u;
    }
#pragma unroll
  for (int off = 32; off >= 1; off >>= 1) {
    s += __shfl_xor(s, off, 64);
    s2 += __shfl_xor(s2, off, 64);
  }
  float mu = s * (1.0f / kH);
  float var = s2 * (1.0f / kH) - mu * mu;
  float rs = rsqrtf(var + 1e-5f);
  int c0 = lane * 16;
#pragma unroll
  for (int j = 0; j < 4; ++j) {
    f32x4 gg = *(const f32x4*)(g + c0 + j * 4);
    f32x4 bb = *(const f32x4*)(b + c0 + j * 4);
    f32x4 o;
#pragma unroll
    for (int t = 0; t < 4; ++t) o[t] = (v[j][t] - mu) * rs * gg[t] + bb[t];
    *(f32x4*)(out + base + j * 4) = o;
  }
}

extern "C" void kernel_launch(void* const* d_in, const int* in_sizes, int n_in,
                              void* d_out, int out_size, void* d_ws, size_t ws_size,
                              hipStream_t stream) {
  const float* x = (const float*)d_in[0];
  const float* We1 = (const float*)d_in[1];
  const float* be1 = (const float*)d_in[2];
  const float* We2 = (const float*)d_in[3];
  const float* be2 = (const float*)d_in[4];
  const float* Wq = (const float*)d_in[5];
  const float* bq = (const float*)d_in[6];
  const float* Wk = (const float*)d_in[7];
  const float* bk = (const float*)d_in[8];
  const float* Wv = (const float*)d_in[9];
  const float* bv = (const float*)d_in[10];
  const float* ln_g = (const float*)d_in[11];
  const float* ln_b = (const float*)d_in[12];
  const int* curp = (const int*)d_in[13];
  float* out = (float*)d_out;

  char* ws = (char*)d_ws;
  const size_t MB = 1ull << 20;
  // Fixed base layout (342 MB):
  bf16_t* stacked = (bf16_t*)(ws);             // [E][M][H] 256MB
  bf16_t* xb = (bf16_t*)(ws + 256 * MB);       // [M][H]    32MB
  bf16_t* boostb = (bf16_t*)(ws + 288 * MB);   // [M][H]    32MB
  bf16_t* wA = (bf16_t*)(ws + 320 * MB);       // [DH][H]    8MB (per-expert We1^T)
  bf16_t* wB = (bf16_t*)(ws + 328 * MB);       // [H][DH]    8MB (per-expert We2^T)
  bf16_t* WqT = (bf16_t*)(ws + 336 * MB);      // 2MB
  bf16_t* WkC = (bf16_t*)(ws + 338 * MB);      // 2MB
  bf16_t* WvT = (bf16_t*)(ws + 340 * MB);      // 2MB
  char* dyn = ws + 342 * MB;
  size_t rem = ws_size > 342 * MB ? ws_size - 342 * MB : 0;
  int nchunk;
  if (rem >= 128 * MB) nchunk = 1;        // h 128MB
  else if (rem >= 64 * MB) nchunk = 2;    // h 64MB
  else nchunk = 4;                        // h 32MB (floor 374MB)
  bf16_t* hbuf = (bf16_t*)dyn;
  bf16_t* qb_ = hbuf;            // 32MB  (h dead)
  bf16_t* qkb = boostb;          // 32MB  (boost dead)
  bf16_t* mixb = xb;             // 32MB  (xb dead after q GEMM)
  float* yf = (float*)ws;        // 64MB  (stacked dead after scores_mix)

  const int Mc = kM / nchunk;
  const size_t MH = (size_t)kM * kH;
  const u32 kLds = 163840;
  dim3 blk(256), blk5(512);

  cvt_flat_kernel<<<(kM * kH) / 1024, blk, 0, stream>>>(x, xb, (kM * kH) / 4);
  cvt_flat_kernel<<<(kH * kH) / 1024, blk, 0, stream>>>(Wk, WkC, (kH * kH) / 4);
  transpose_cvt_kernel<<<dim3(kH / 32, kH / 32), blk, 0, stream>>>(Wq, WqT, kH, kH);
  transpose_cvt_kernel<<<dim3(kH / 32, kH / 32), blk, 0, stream>>>(Wv, WvT, kH, kH);

  for (int i = 0; i < kE; ++i) {
    transpose_cvt_kernel<<<dim3(kDH / 32, kH / 32), blk, 0, stream>>>(
        We1 + (size_t)i * kH * kDH, wA, kH, kDH);
    transpose_cvt_kernel<<<dim3(kH / 32, kDH / 32), blk, 0, stream>>>(
        We2 + (size_t)i * kH * kDH, wB, kDH, kH);
    for (int c = 0; c < nchunk; ++c) {
      const size_t ro = (size_t)c * Mc * kH;
      const bf16_t* Ain = ((i == 0) ? xb : boostb) + ro;
      {
        int nwg = (Mc / 256) * (kDH / 256);
        gemm256_kernel<0><<<nwg, blk5, kLds, stream>>>(
            Ain, wA, Mc, kDH, kH, nwg, be1 + (size_t)i * kDH, hbuf,
            nullptr, nullptr, nullptr, nullptr, nullptr, curp, i);
      }
      int nwg = (Mc / 256) * (kH / 256);
      const bf16_t* binb = ((i == 0) ? xb : boostb) + ro;
      gemm256_kernel<4><<<nwg, blk5, kLds, stream>>>(
          hbuf, wB, Mc, kH, kDH, nwg, be2 + (size_t)i * kH, nullptr,
          binb, boostb + ro, stacked + (size_t)i * MH + ro,
          nullptr, nullptr, curp, i);
    }
  }

  const int nwgH = (kM / 256) * (kH / 256);
  // q = x Wq + bq
  gemm256_kernel<2><<<nwgH, blk5, kLds, stream>>>(
      xb, WqT, kM, kH, kH, nwgH, bq, qb_,
      nullptr, nullptr, nullptr, nullptr, nullptr, curp, 0);
  // qk[m,h] = sum_d q[m,d] * Wk[h,d]
  gemm256_kernel<2><<<nwgH, blk5, kLds, stream>>>(
      qb_, WkC, kM, kH, kH, nwgH, nullptr, qkb,
      nullptr, nullptr, nullptr, nullptr, nullptr, curp, 0);
  // scores -> softmax -> mix
  scores_mix_kernel<<<dim3(kM / 4), blk, 0, stream>>>(qkb, qb_, bk, stacked, mixb, curp);
  // y = x + mix Wv + bv
  gemm256_kernel<3><<<nwgH, blk5, kLds, stream>>>(
      mixb, WvT, kM, kH, kH, nwgH, bv, nullptr,
      nullptr, nullptr, nullptr, x, yf, curp, 0);
  // LayerNorm
  layernorm_kernel<<<dim3(kM / 4), blk, 0, stream>>>(yf, ln_g, ln_b, out);
}